// Round 1
// baseline (125.035 us; speedup 1.0000x reference)
//
#include <hip/hip_runtime.h>

#define B_ 512
#define C_ 64
#define H_ 128
#define P_ 16
#define G_ 2
#define EPS 1e-5f

// ---------------- kernel 1: layernorms + hat0 (b-independent) ----------------
__global__ __launch_bounds__(256) void prep_kernel(
    const float* __restrict__ emb_column,  // [C,H]
    const float* __restrict__ emb_prompt,  // [P,H]
    const float* __restrict__ lin_w,       // [H,2H]
    const float* __restrict__ lin_b,       // [H]
    const float* __restrict__ ln_col_w, const float* __restrict__ ln_col_b,
    const float* __restrict__ ln_pr_w,  const float* __restrict__ ln_pr_b,
    float* __restrict__ ec,    // ws: [C,H] layernormed emb_column
    float* __restrict__ hat0)  // ws: [P,H] = ep@W1^T + lin_b + ep
{
    __shared__ __align__(16) float ep_s[P_ * H_];
    const int t = threadIdx.x;

    // ep layernorm: 16 rows, 16 threads/row, 8 elems each (xor-shuffle within 16 lanes)
    {
        const int r = t >> 4, j = t & 15;
        float v[8]; float s = 0.f, s2 = 0.f;
        #pragma unroll
        for (int i = 0; i < 8; ++i) {
            v[i] = emb_prompt[r * H_ + j + 16 * i];
            s += v[i]; s2 += v[i] * v[i];
        }
        #pragma unroll
        for (int m = 1; m < 16; m <<= 1) { s += __shfl_xor(s, m, 64); s2 += __shfl_xor(s2, m, 64); }
        const float mean = s * (1.f / H_);
        const float rs = rsqrtf(s2 * (1.f / H_) - mean * mean + EPS);
        #pragma unroll
        for (int i = 0; i < 8; ++i) {
            const int h = j + 16 * i;
            ep_s[r * H_ + h] = (v[i] - mean) * rs * ln_pr_w[h] + ln_pr_b[h];
        }
    }
    // ec layernorm: 64 rows, 4 threads/row, 32 elems each
    {
        const int r = t >> 2, j = t & 3;
        float v[32]; float s = 0.f, s2 = 0.f;
        #pragma unroll
        for (int i = 0; i < 32; ++i) {
            v[i] = emb_column[r * H_ + j + 4 * i];
            s += v[i]; s2 += v[i] * v[i];
        }
        #pragma unroll
        for (int m = 1; m < 4; m <<= 1) { s += __shfl_xor(s, m, 64); s2 += __shfl_xor(s2, m, 64); }
        const float mean = s * (1.f / H_);
        const float rs = rsqrtf(s2 * (1.f / H_) - mean * mean + EPS);
        #pragma unroll
        for (int i = 0; i < 32; ++i) {
            const int h = j + 4 * i;
            ec[r * H_ + h] = (v[i] - mean) * rs * ln_col_w[h] + ln_col_b[h];
        }
    }
    __syncthreads();
    // hat0[p,h] = sum_k ep[p,k]*lin_w[h,k] + lin_b[h] + ep[p,h]
    {
        const int h = t & 127;
        const int pb = (t >> 7) * 8;
        float acc[8];
        #pragma unroll
        for (int i = 0; i < 8; ++i) acc[i] = lin_b[h] + ep_s[(pb + i) * H_ + h];
        const float4* w14 = (const float4*)(lin_w + h * (2 * H_));
        for (int k = 0; k < H_ / 4; ++k) {
            const float4 w = w14[k];
            #pragma unroll
            for (int i = 0; i < 8; ++i) {
                const float4 e = ((const float4*)(ep_s + (pb + i) * H_))[k];
                acc[i] += e.x * w.x + e.y * w.y + e.z * w.z + e.w * w.w;
            }
        }
        #pragma unroll
        for (int i = 0; i < 8; ++i) hat0[(pb + i) * H_ + h] = acc[i];
    }
}

// ---------------- kernel 2: one block per batch element ----------------
__global__ __launch_bounds__(256) void main_kernel(
    const float* __restrict__ x,         // [B,C,H]
    const float* __restrict__ x_prompt,  // [B,P,H]
    const float* __restrict__ lin_w,     // [H,2H]
    const float* __restrict__ expand_w,  // [P]
    const float* __restrict__ gn_w, const float* __restrict__ gn_b,  // [P]
    const float* __restrict__ ec,        // [C,H]
    const float* __restrict__ hat0,      // [P,H]
    float* __restrict__ out)             // [B,P,H]
{
    __shared__ __align__(16) float xs[C_ * H_];     // 32 KB
    __shared__ __align__(16) float hat_s[P_ * H_];  // 8 KB
    __shared__ __align__(16) float sm[P_ * C_];     // 4 KB  scores -> softmax weights
    __shared__ float red[16];
    __shared__ float stat[4];   // Xsum, Xsq, R1=sum relu(x), R2=sum relu(x)^2
    __shared__ float s1_s[P_], s2_s[P_];
    __shared__ float cA[P_], cB[P_], cD[P_];

    const int t = threadIdx.x;
    const int b = blockIdx.x;

    // ---- phase A: stage x[b] -> LDS, accumulate the 4 reduction stats ----
    {
        const float4* x4 = (const float4*)(x + (size_t)b * (C_ * H_));
        float4* xs4 = (float4*)xs;
        float xsum = 0.f, xsq = 0.f, r1 = 0.f, r2 = 0.f;
        #pragma unroll
        for (int i = 0; i < 8; ++i) {
            const float4 v = x4[t + 256 * i];
            xs4[t + 256 * i] = v;
            xsum += (v.x + v.y) + (v.z + v.w);
            xsq  += (v.x * v.x + v.y * v.y) + (v.z * v.z + v.w * v.w);
            const float rx = fmaxf(v.x, 0.f), ry = fmaxf(v.y, 0.f);
            const float rz = fmaxf(v.z, 0.f), rw = fmaxf(v.w, 0.f);
            r1 += (rx + ry) + (rz + rw);
            r2 += (rx * rx + ry * ry) + (rz * rz + rw * rw);
        }
        #pragma unroll
        for (int m = 1; m < 64; m <<= 1) {
            xsum += __shfl_xor(xsum, m, 64);
            xsq  += __shfl_xor(xsq,  m, 64);
            r1   += __shfl_xor(r1,   m, 64);
            r2   += __shfl_xor(r2,   m, 64);
        }
        if ((t & 63) == 0) {
            const int w = t >> 6;
            red[w * 4 + 0] = xsum; red[w * 4 + 1] = xsq;
            red[w * 4 + 2] = r1;   red[w * 4 + 3] = r2;
        }
    }
    __syncthreads();
    if (t < 4) stat[t] = red[t] + red[4 + t] + red[8 + t] + red[12 + t];

    // ---- phase B: hat[p,h] = hat0 + x_prompt@W2^T + x_prompt ----
    {
        const int h = t & 127;
        const int pb = __builtin_amdgcn_readfirstlane((t >> 7) * 8);  // wave-uniform
        const float* xpg = x_prompt + (size_t)b * (P_ * H_) + pb * H_;
        float acc[8];
        #pragma unroll
        for (int i = 0; i < 8; ++i)
            acc[i] = hat0[(pb + i) * H_ + h] + xpg[i * H_ + h];
        const float4* w24 = (const float4*)(lin_w + h * (2 * H_) + H_);
        for (int k = 0; k < H_ / 4; ++k) {
            const float4 w = w24[k];
            #pragma unroll
            for (int i = 0; i < 8; ++i) {
                const float* xr = xpg + i * H_ + 4 * k;  // wave-uniform address -> s_load
                acc[i] += xr[0] * w.x + xr[1] * w.y + xr[2] * w.z + xr[3] * w.w;
            }
        }
        #pragma unroll
        for (int i = 0; i < 8; ++i) hat_s[(pb + i) * H_ + h] = acc[i];
    }
    __syncthreads();

    // ---- phase C: scores s[p,c] = sum_h hat[p,h]*ec[c,h]; and per-p S1/S2 ----
    {
        const int c = t & 63;
        const int p0 = __builtin_amdgcn_readfirstlane(t >> 6);  // wave-uniform
        float acc[4] = {0.f, 0.f, 0.f, 0.f};
        const float4* ec4 = (const float4*)(ec + c * H_);
        for (int k = 0; k < H_ / 4; ++k) {
            const float4 e = ec4[k];
            #pragma unroll
            for (int i = 0; i < 4; ++i) {
                const float4 hv = ((const float4*)(hat_s + (p0 + 4 * i) * H_))[k];
                acc[i] += hv.x * e.x + hv.y * e.y + hv.z * e.z + hv.w * e.w;
            }
        }
        #pragma unroll
        for (int i = 0; i < 4; ++i) sm[(p0 + 4 * i) * C_ + c] = acc[i];
    }
    if (t < P_) {
        // xe = relu(ew*x) = Ap*relu(x) + Bp*x  with Ap=|ew|, Bp=min(ew,0)
        const float ew = expand_w[t];
        const float Ap = fabsf(ew);
        const float Bp = fminf(ew, 0.f);
        s1_s[t] = Ap * stat[2] + Bp * stat[0];
        s2_s[t] = ew * ew * (ew >= 0.f ? stat[3] : (stat[1] - stat[3]));
    }
    __syncthreads();

    // ---- phase D: group stats -> per-p affine coeffs; softmax over c ----
    if (t < P_) {
        const int g = t >> 3;
        float S1 = 0.f, S2 = 0.f;
        #pragma unroll
        for (int q = 0; q < 8; ++q) { S1 += s1_s[g * 8 + q]; S2 += s2_s[g * 8 + q]; }
        const float invN = 1.f / (float)((P_ / G_) * C_ * H_);
        const float mu = S1 * invN;
        const float var = S2 * invN - mu * mu;
        const float rs = rsqrtf(var + EPS);
        const float a = rs * gn_w[t];
        const float ew = expand_w[t];
        cA[t] = a * fabsf(ew);          // coeff on TR = sum_c m*relu(x)
        cB[t] = a * fminf(ew, 0.f) + 1.f;  // coeff on U = sum_c m*x (+1 = residual x)
        cD[t] = gn_b[t] - mu * a;       // constant (sum_c m == 1)
    }
    {
        const int p = t >> 4, j = t & 15;
        float v0 = sm[p * C_ + j],      v1 = sm[p * C_ + j + 16];
        float v2 = sm[p * C_ + j + 32], v3 = sm[p * C_ + j + 48];
        float mx = fmaxf(fmaxf(v0, v1), fmaxf(v2, v3));
        #pragma unroll
        for (int m = 1; m < 16; m <<= 1) mx = fmaxf(mx, __shfl_xor(mx, m, 64));
        const float e0 = __expf(v0 - mx), e1 = __expf(v1 - mx);
        const float e2 = __expf(v2 - mx), e3 = __expf(v3 - mx);
        float ssum = (e0 + e1) + (e2 + e3);
        #pragma unroll
        for (int m = 1; m < 16; m <<= 1) ssum += __shfl_xor(ssum, m, 64);
        const float inv = 1.f / ssum;
        sm[p * C_ + j]      = e0 * inv; sm[p * C_ + j + 16] = e1 * inv;
        sm[p * C_ + j + 32] = e2 * inv; sm[p * C_ + j + 48] = e3 * inv;
    }
    __syncthreads();

    // ---- phase E: out[p,h] = cA*TR + cB*U + cD ----
    {
        const int h = t & 127;
        const int pb = __builtin_amdgcn_readfirstlane((t >> 7) * 8);
        float U[8], TR[8];
        #pragma unroll
        for (int i = 0; i < 8; ++i) { U[i] = 0.f; TR[i] = 0.f; }
        for (int c4 = 0; c4 < C_ / 4; ++c4) {
            float xv[4], rv[4];
            #pragma unroll
            for (int j = 0; j < 4; ++j) {
                xv[j] = xs[(c4 * 4 + j) * H_ + h];   // 2-way bank alias: free
                rv[j] = fmaxf(xv[j], 0.f);
            }
            #pragma unroll
            for (int i = 0; i < 8; ++i) {
                const float4 mv = ((const float4*)(sm + (pb + i) * C_))[c4];  // broadcast
                U[i]  += mv.x * xv[0] + mv.y * xv[1] + mv.z * xv[2] + mv.w * xv[3];
                TR[i] += mv.x * rv[0] + mv.y * rv[1] + mv.z * rv[2] + mv.w * rv[3];
            }
        }
        float* ob = out + (size_t)b * (P_ * H_);
        #pragma unroll
        for (int i = 0; i < 8; ++i)
            ob[(pb + i) * H_ + h] = cA[pb + i] * TR[i] + cB[pb + i] * U[i] + cD[pb + i];
    }
}

extern "C" void kernel_launch(void* const* d_in, const int* in_sizes, int n_in,
                              void* d_out, int out_size, void* d_ws, size_t ws_size,
                              hipStream_t stream) {
    const float* x          = (const float*)d_in[0];
    const float* x_prompt   = (const float*)d_in[1];
    const float* emb_column = (const float*)d_in[2];
    const float* emb_prompt = (const float*)d_in[3];
    const float* lin_w      = (const float*)d_in[4];
    const float* lin_b      = (const float*)d_in[5];
    const float* ln_col_w   = (const float*)d_in[6];
    const float* ln_col_b   = (const float*)d_in[7];
    const float* ln_pr_w    = (const float*)d_in[8];
    const float* ln_pr_b    = (const float*)d_in[9];
    const float* expand_w   = (const float*)d_in[10];
    const float* gn_w       = (const float*)d_in[11];
    const float* gn_b       = (const float*)d_in[12];
    float* out  = (float*)d_out;
    float* ec   = (float*)d_ws;          // [C,H]
    float* hat0 = ec + C_ * H_;          // [P,H]

    prep_kernel<<<1, 256, 0, stream>>>(emb_column, emb_prompt, lin_w, lin_b,
                                       ln_col_w, ln_col_b, ln_pr_w, ln_pr_b,
                                       ec, hat0);
    main_kernel<<<B_, 256, 0, stream>>>(x, x_prompt, lin_w, expand_w, gn_w, gn_b,
                                        ec, hat0, out);
}

// Round 3
// 103.338 us; speedup vs baseline: 1.2100x; 1.2100x over previous
//
#include <hip/hip_runtime.h>

#define B_ 512
#define C_ 64
#define H_ 128
#define P_ 16
#define G_ 2
#define EPS 1e-5f

// LDS row strides (bf16 units) chosen for bank behavior + 16B frag alignment
#define XS_S 130   // xs_bf [C][XS_S]: bank (c + h/2)%32 -> 2-way on column reads
#define HB_S 136   // xp/hat [P][HB_S]: 272B rows, 16B-aligned frags
#define MB_S 72    // m_bf [P][MB_S]

typedef __attribute__((ext_vector_type(8))) short bf16x8;
typedef __attribute__((ext_vector_type(4))) float f32x4;

__device__ __forceinline__ unsigned short f2bf(float f) {
    union { float f; unsigned u; } v; v.f = f;
    return (unsigned short)((v.u + 0x7FFFu + ((v.u >> 16) & 1u)) >> 16);
}
__device__ __forceinline__ float bf2f(unsigned short h) {
    union { unsigned u; float f; } v; v.u = ((unsigned)h) << 16; return v.f;
}
__device__ __forceinline__ unsigned packbf(float lo, float hi) {
    return (unsigned)f2bf(lo) | ((unsigned)f2bf(hi) << 16);
}
// split two floats into packed hi-pair and lo-pair (double-bf16)
__device__ __forceinline__ void split2(float a, float b, unsigned& hi, unsigned& lo) {
    const unsigned short ah = f2bf(a), bh = f2bf(b);
    const unsigned short al = f2bf(a - bf2f(ah)), bl = f2bf(b - bf2f(bh));
    hi = (unsigned)ah | ((unsigned)bh << 16);
    lo = (unsigned)al | ((unsigned)bl << 16);
}
// relu on 8 packed bf16: zero each half whose sign bit is set
__device__ __forceinline__ bf16x8 relu8(bf16x8 x) {
    union { bf16x8 v; unsigned u[4]; } a; a.v = x;
    #pragma unroll
    for (int i = 0; i < 4; ++i) {
        unsigned s = a.u[i] & 0x80008000u;
        a.u[i] &= ~((s >> 15) * 0xFFFFu);
    }
    return a.v;
}

// ---------------- kernel 1 (8 blocks): layernorms + hat0 + hi/lo weight prep --
__global__ __launch_bounds__(256) void prep_kernel(
    const float* __restrict__ emb_column,  // [C,H]
    const float* __restrict__ emb_prompt,  // [P,H]
    const float* __restrict__ lin_w,       // [H,2H]
    const float* __restrict__ lin_b,       // [H]
    const float* __restrict__ ln_col_w, const float* __restrict__ ln_col_b,
    const float* __restrict__ ln_pr_w,  const float* __restrict__ ln_pr_b,
    float* __restrict__ hat0,              // ws: [P,H] = ep@W1^T + lin_b + ep
    unsigned short* __restrict__ ec_hi,    // ws: [C,H] layernormed emb_column hi
    unsigned short* __restrict__ ec_lo,    // ws: [C,H] lo
    unsigned short* __restrict__ w2_hi,    // ws: [H,H] hi, [h][k]=lin_w[h][H+k]
    unsigned short* __restrict__ w2_lo)    // ws: [H,H] lo
{
    __shared__ __align__(16) float ep_s[P_ * H_];
    const int t = threadIdx.x;
    const int blk = blockIdx.x;

    // ep layernorm (all 16 rows, redundantly per block): 16 threads/row
    {
        const int r = t >> 4, j = t & 15;
        float v[8]; float s = 0.f, s2 = 0.f;
        #pragma unroll
        for (int i = 0; i < 8; ++i) {
            v[i] = emb_prompt[r * H_ + j + 16 * i];
            s += v[i]; s2 += v[i] * v[i];
        }
        #pragma unroll
        for (int m = 1; m < 16; m <<= 1) { s += __shfl_xor(s, m, 64); s2 += __shfl_xor(s2, m, 64); }
        const float mean = s * (1.f / H_);
        const float rs = rsqrtf(s2 * (1.f / H_) - mean * mean + EPS);
        #pragma unroll
        for (int i = 0; i < 8; ++i) {
            const int h = j + 16 * i;
            ep_s[r * H_ + h] = (v[i] - mean) * rs * ln_pr_w[h] + ln_pr_b[h];
        }
    }
    // ec layernorm -> hi/lo, rows blk*8 .. blk*8+7 (32 threads/row)
    {
        const int r = blk * 8 + (t >> 5), j = t & 31;
        float v[4]; float s = 0.f, s2 = 0.f;
        #pragma unroll
        for (int i = 0; i < 4; ++i) {
            v[i] = emb_column[r * H_ + j + 32 * i];
            s += v[i]; s2 += v[i] * v[i];
        }
        #pragma unroll
        for (int m = 1; m < 32; m <<= 1) { s += __shfl_xor(s, m, 64); s2 += __shfl_xor(s2, m, 64); }
        const float mean = s * (1.f / H_);
        const float rs = rsqrtf(s2 * (1.f / H_) - mean * mean + EPS);
        #pragma unroll
        for (int i = 0; i < 4; ++i) {
            const int h = j + 32 * i;
            const float val = (v[i] - mean) * rs * ln_col_w[h] + ln_col_b[h];
            const unsigned short hi = f2bf(val);
            ec_hi[r * H_ + h] = hi;
            ec_lo[r * H_ + h] = f2bf(val - bf2f(hi));
        }
    }
    // w2 hi/lo slice: 2048 elements per block, 8 per thread
    {
        const int flat = blk * 2048 + t * 8;
        const int h = flat >> 7, k0 = flat & 127;
        const float4* src = (const float4*)(lin_w + h * (2 * H_) + H_ + k0);
        const float4 q0 = src[0], q1 = src[1];
        uint4 ph, pl;
        split2(q0.x, q0.y, ph.x, pl.x);
        split2(q0.z, q0.w, ph.y, pl.y);
        split2(q1.x, q1.y, ph.z, pl.z);
        split2(q1.z, q1.w, ph.w, pl.w);
        *(uint4*)(w2_hi + flat) = ph;
        *(uint4*)(w2_lo + flat) = pl;
    }
    __syncthreads();
    // hat0 rows blk*2, blk*2+1: one (p,h) per thread, fp32
    {
        const int p = blk * 2 + (t >> 7);
        const int h = t & 127;
        float acc = lin_b[h] + ep_s[p * H_ + h];
        const float4* w1 = (const float4*)(lin_w + h * (2 * H_));
        const float4* e4 = (const float4*)(ep_s + p * H_);
        for (int k = 0; k < H_ / 4; ++k) {
            const float4 w = w1[k]; const float4 e = e4[k];
            acc += e.x * w.x + e.y * w.y + e.z * w.z + e.w * w.w;
        }
        hat0[p * H_ + h] = acc;
    }
}

// ---------------- kernel 2: one block per batch element, MFMA + hi/lo --------
__global__ __launch_bounds__(256) void main_kernel(
    const float* __restrict__ x,         // [B,C,H]
    const float* __restrict__ x_prompt,  // [B,P,H]
    const float* __restrict__ expand_w,  // [P]
    const float* __restrict__ gn_w, const float* __restrict__ gn_b,  // [P]
    const float* __restrict__ hat0,             // [P,H] fp32
    const unsigned short* __restrict__ ec_hi,   // [C,H]
    const unsigned short* __restrict__ ec_lo,
    const unsigned short* __restrict__ w2_hi,   // [H,H]
    const unsigned short* __restrict__ w2_lo,
    float* __restrict__ out)             // [B,P,H]
{
    __shared__ __align__(16) unsigned short xs_bf[C_ * XS_S];    // 16640 B
    __shared__ __align__(16) unsigned short xp_hi[P_ * HB_S];    // 4352 B
    __shared__ __align__(16) unsigned short xp_lo[P_ * HB_S];    // 4352 B
    __shared__ __align__(16) unsigned short hat_hi[P_ * HB_S];   // 4352 B
    __shared__ __align__(16) unsigned short hat_lo[P_ * HB_S];   // 4352 B
    __shared__ __align__(16) float sm[P_ * C_];                  // 4096 B
    __shared__ __align__(16) unsigned short m_bf[P_ * MB_S];     // 2304 B
    __shared__ float red[16];
    __shared__ float stat[4];   // Xsum, Xsq, R1=sum relu(x), R2=sum relu(x)^2
    __shared__ float s1_s[P_], s2_s[P_];
    __shared__ float cA[P_], cB[P_], cD[P_];

    const int t = threadIdx.x;
    const int b = blockIdx.x;
    const int lane = t & 63;
    const int w = t >> 6;       // wave id 0..3
    const int nl = lane & 15;   // MFMA n/m lane coord
    const int quad = lane >> 4; // MFMA quad

    // ---- phase A: x[b] -> bf16 LDS + stats; x_prompt[b] -> hi/lo LDS ----
    {
        const float4* x4 = (const float4*)(x + (size_t)b * (C_ * H_));
        float xsum = 0.f, xsq = 0.f, r1 = 0.f, r2 = 0.f;
        #pragma unroll
        for (int i = 0; i < 8; ++i) {
            const int idx = t + 256 * i;
            const float4 v = x4[idx];
            const int c = idx >> 5;
            const int h0 = (idx & 31) * 4;
            unsigned* dst = (unsigned*)(xs_bf + c * XS_S + h0);
            dst[0] = packbf(v.x, v.y);
            dst[1] = packbf(v.z, v.w);
            xsum += (v.x + v.y) + (v.z + v.w);
            xsq  += (v.x * v.x + v.y * v.y) + (v.z * v.z + v.w * v.w);
            const float rx = fmaxf(v.x, 0.f), ry = fmaxf(v.y, 0.f);
            const float rz = fmaxf(v.z, 0.f), rw = fmaxf(v.w, 0.f);
            r1 += (rx + ry) + (rz + rw);
            r2 += (rx * rx + ry * ry) + (rz * rz + rw * rw);
        }
        #pragma unroll
        for (int m = 1; m < 64; m <<= 1) {
            xsum += __shfl_xor(xsum, m, 64);
            xsq  += __shfl_xor(xsq,  m, 64);
            r1   += __shfl_xor(r1,   m, 64);
            r2   += __shfl_xor(r2,   m, 64);
        }
        if (lane == 0) {
            red[w * 4 + 0] = xsum; red[w * 4 + 1] = xsq;
            red[w * 4 + 2] = r1;   red[w * 4 + 3] = r2;
        }
        // xp -> hi/lo LDS: 8 consecutive values per thread
        const float4* xp4 = (const float4*)(x_prompt + (size_t)b * (P_ * H_));
        const float4 a0 = xp4[2 * t], a1 = xp4[2 * t + 1];
        const int p = t >> 4, hh = (t & 15) * 8;
        uint4 ph, pl;
        split2(a0.x, a0.y, ph.x, pl.x);
        split2(a0.z, a0.w, ph.y, pl.y);
        split2(a1.x, a1.y, ph.z, pl.z);
        split2(a1.z, a1.w, ph.w, pl.w);
        *(uint4*)(xp_hi + p * HB_S + hh) = ph;
        *(uint4*)(xp_lo + p * HB_S + hh) = pl;
    }
    __syncthreads();
    if (t < 4) stat[t] = red[t] + red[4 + t] + red[8 + t] + red[12 + t];

    // ---- phase B (MFMA, hi/lo): hat = xp@W2^T + hat0 + xp ; store hi/lo ----
    {
        f32x4 acc[2] = {{0.f,0.f,0.f,0.f},{0.f,0.f,0.f,0.f}};
        #pragma unroll
        for (int kk = 0; kk < 4; ++kk) {
            const bf16x8 a_hi = *(const bf16x8*)(xp_hi + nl * HB_S + kk * 32 + quad * 8);
            const bf16x8 a_lo = *(const bf16x8*)(xp_lo + nl * HB_S + kk * 32 + quad * 8);
            #pragma unroll
            for (int T = 0; T < 2; ++T) {
                const int h = w * 32 + T * 16 + nl;
                const bf16x8 b_hi = *(const bf16x8*)(w2_hi + h * H_ + kk * 32 + quad * 8);
                const bf16x8 b_lo = *(const bf16x8*)(w2_lo + h * H_ + kk * 32 + quad * 8);
                acc[T] = __builtin_amdgcn_mfma_f32_16x16x32_bf16(a_hi, b_hi, acc[T], 0, 0, 0);
                acc[T] = __builtin_amdgcn_mfma_f32_16x16x32_bf16(a_lo, b_hi, acc[T], 0, 0, 0);
                acc[T] = __builtin_amdgcn_mfma_f32_16x16x32_bf16(a_hi, b_lo, acc[T], 0, 0, 0);
            }
        }
        const float* xpg = x_prompt + (size_t)b * (P_ * H_);
        #pragma unroll
        for (int T = 0; T < 2; ++T) {
            const int h = w * 32 + T * 16 + nl;
            #pragma unroll
            for (int r = 0; r < 4; ++r) {
                const int p = quad * 4 + r;
                const float val = acc[T][r] + hat0[p * H_ + h] + xpg[p * H_ + h];
                const unsigned short hi = f2bf(val);
                hat_hi[p * HB_S + h] = hi;
                hat_lo[p * HB_S + h] = f2bf(val - bf2f(hi));
            }
        }
    }
    __syncthreads();

    // ---- group-norm per-p partial sums (uses stat) ----
    if (t < P_) {
        const float ew = expand_w[t];
        const float Ap = fabsf(ew);
        const float Bp = fminf(ew, 0.f);
        s1_s[t] = Ap * stat[2] + Bp * stat[0];
        s2_s[t] = ew * ew * (ew >= 0.f ? stat[3] : (stat[1] - stat[3]));
    }
    // ---- phase C (MFMA, hi/lo): scores[p][c] = hat @ ec^T ----
    {
        f32x4 acc = {0.f, 0.f, 0.f, 0.f};
        const int c = w * 16 + nl;
        #pragma unroll
        for (int kk = 0; kk < 4; ++kk) {
            const bf16x8 a_hi = *(const bf16x8*)(hat_hi + nl * HB_S + kk * 32 + quad * 8);
            const bf16x8 a_lo = *(const bf16x8*)(hat_lo + nl * HB_S + kk * 32 + quad * 8);
            const bf16x8 b_hi = *(const bf16x8*)(ec_hi + c * H_ + kk * 32 + quad * 8);
            const bf16x8 b_lo = *(const bf16x8*)(ec_lo + c * H_ + kk * 32 + quad * 8);
            acc = __builtin_amdgcn_mfma_f32_16x16x32_bf16(a_hi, b_hi, acc, 0, 0, 0);
            acc = __builtin_amdgcn_mfma_f32_16x16x32_bf16(a_lo, b_hi, acc, 0, 0, 0);
            acc = __builtin_amdgcn_mfma_f32_16x16x32_bf16(a_hi, b_lo, acc, 0, 0, 0);
        }
        #pragma unroll
        for (int r = 0; r < 4; ++r) sm[(quad * 4 + r) * C_ + c] = acc[r];
    }
    __syncthreads();

    // ---- phase D: coeffs + softmax (fp32) -> m_bf ----
    if (t < P_) {
        const int g = t >> 3;
        float S1 = 0.f, S2 = 0.f;
        #pragma unroll
        for (int q = 0; q < 8; ++q) { S1 += s1_s[g * 8 + q]; S2 += s2_s[g * 8 + q]; }
        const float invN = 1.f / (float)((P_ / G_) * C_ * H_);
        const float mu = S1 * invN;
        const float var = S2 * invN - mu * mu;
        const float rs = rsqrtf(var + EPS);
        const float a = rs * gn_w[t];
        const float ew = expand_w[t];
        cA[t] = a * fabsf(ew);             // coeff on TR = sum_c m*relu(x)
        cB[t] = a * fminf(ew, 0.f) + 1.f;  // coeff on U = sum_c m*x (+1 residual)
        cD[t] = gn_b[t] - mu * a;          // constant (sum_c m == 1)
    }
    {
        const int p = t >> 4, j = t & 15;
        float v0 = sm[p * C_ + j],      v1 = sm[p * C_ + j + 16];
        float v2 = sm[p * C_ + j + 32], v3 = sm[p * C_ + j + 48];
        float mx = fmaxf(fmaxf(v0, v1), fmaxf(v2, v3));
        #pragma unroll
        for (int m = 1; m < 16; m <<= 1) mx = fmaxf(mx, __shfl_xor(mx, m, 64));
        const float e0 = __expf(v0 - mx), e1 = __expf(v1 - mx);
        const float e2 = __expf(v2 - mx), e3 = __expf(v3 - mx);
        float ssum = (e0 + e1) + (e2 + e3);
        #pragma unroll
        for (int m = 1; m < 16; m <<= 1) ssum += __shfl_xor(ssum, m, 64);
        const float inv = 1.f / ssum;
        m_bf[p * MB_S + j]      = f2bf(e0 * inv);
        m_bf[p * MB_S + j + 16] = f2bf(e1 * inv);
        m_bf[p * MB_S + j + 32] = f2bf(e2 * inv);
        m_bf[p * MB_S + j + 48] = f2bf(e3 * inv);
    }
    __syncthreads();

    // ---- phase E (MFMA): U = m@x, TR = m@relu(x); out = cA*TR + cB*U + cD ----
    {
        f32x4 aU[2] = {{0.f,0.f,0.f,0.f},{0.f,0.f,0.f,0.f}};
        f32x4 aT[2] = {{0.f,0.f,0.f,0.f},{0.f,0.f,0.f,0.f}};
        #pragma unroll
        for (int kk = 0; kk < 2; ++kk) {
            const bf16x8 af = *(const bf16x8*)(m_bf + nl * MB_S + kk * 32 + quad * 8);
            #pragma unroll
            for (int T = 0; T < 2; ++T) {
                const int h = w * 32 + T * 16 + nl;
                // B-frag: x[c][h] for c = kk*32 + quad*8 + j (column read, 2-way banks)
                union { bf16x8 v; unsigned short s[8]; } bu;
                const int c0 = kk * 32 + quad * 8;
                #pragma unroll
                for (int j = 0; j < 8; ++j) bu.s[j] = xs_bf[(c0 + j) * XS_S + h];
                aU[T] = __builtin_amdgcn_mfma_f32_16x16x32_bf16(af, bu.v, aU[T], 0, 0, 0);
                const bf16x8 br = relu8(bu.v);
                aT[T] = __builtin_amdgcn_mfma_f32_16x16x32_bf16(af, br, aT[T], 0, 0, 0);
            }
        }
        float* ob = out + (size_t)b * (P_ * H_);
        #pragma unroll
        for (int T = 0; T < 2; ++T) {
            const int h = w * 32 + T * 16 + nl;
            #pragma unroll
            for (int r = 0; r < 4; ++r) {
                const int p = quad * 4 + r;
                ob[p * H_ + h] = cA[p] * aT[T][r] + cB[p] * aU[T][r] + cD[p];
            }
        }
    }
}

extern "C" void kernel_launch(void* const* d_in, const int* in_sizes, int n_in,
                              void* d_out, int out_size, void* d_ws, size_t ws_size,
                              hipStream_t stream) {
    const float* x          = (const float*)d_in[0];
    const float* x_prompt   = (const float*)d_in[1];
    const float* emb_column = (const float*)d_in[2];
    const float* emb_prompt = (const float*)d_in[3];
    const float* lin_w      = (const float*)d_in[4];
    const float* lin_b      = (const float*)d_in[5];
    const float* ln_col_w   = (const float*)d_in[6];
    const float* ln_col_b   = (const float*)d_in[7];
    const float* ln_pr_w    = (const float*)d_in[8];
    const float* ln_pr_b    = (const float*)d_in[9];
    const float* expand_w   = (const float*)d_in[10];
    const float* gn_w       = (const float*)d_in[11];
    const float* gn_b       = (const float*)d_in[12];
    float* out = (float*)d_out;

    float* hat0 = (float*)d_ws;                                 // [P,H] fp32
    unsigned short* ec_hi = (unsigned short*)(hat0 + P_ * H_);  // [C,H]
    unsigned short* ec_lo = ec_hi + C_ * H_;                    // [C,H]
    unsigned short* w2_hi = ec_lo + C_ * H_;                    // [H,H]
    unsigned short* w2_lo = w2_hi + H_ * H_;                    // [H,H]

    prep_kernel<<<8, 256, 0, stream>>>(emb_column, emb_prompt, lin_w, lin_b,
                                       ln_col_w, ln_col_b, ln_pr_w, ln_pr_b,
                                       hat0, ec_hi, ec_lo, w2_hi, w2_lo);
    main_kernel<<<B_, 256, 0, stream>>>(x, x_prompt, expand_w, gn_w, gn_b,
                                        hat0, ec_hi, ec_lo, w2_hi, w2_lo, out);
}

// Round 4
// 100.834 us; speedup vs baseline: 1.2400x; 1.0248x over previous
//
#include <hip/hip_runtime.h>

#define B_ 512
#define C_ 64
#define H_ 128
#define P_ 16
#define G_ 2
#define EPS 1e-5f

// LDS row strides (bf16 units) chosen for bank behavior + 16B frag alignment
#define XS_S 130   // xs_bf [C][XS_S]: bank (c + h/2)%32 -> 2-way on column reads
#define HB_S 136   // xp/hat [P][HB_S]: 272B rows, 16B-aligned frags
#define MB_S 72    // m_bf [P][MB_S]

typedef __attribute__((ext_vector_type(8))) short bf16x8;
typedef __attribute__((ext_vector_type(4))) float f32x4;

__device__ __forceinline__ unsigned short f2bf(float f) {  // round-nearest-even
    union { float f; unsigned u; } v; v.f = f;
    return (unsigned short)((v.u + 0x7FFFu + ((v.u >> 16) & 1u)) >> 16);
}
__device__ __forceinline__ float bf2f(unsigned short h) {
    union { unsigned u; float f; } v; v.u = ((unsigned)h) << 16; return v.f;
}
// cheap round (ties-away) for the phase-E-only x staging: 2 ops per value
__device__ __forceinline__ unsigned packbf_fast(float lo, float hi) {
    union { float f; unsigned u; } a, b; a.f = lo; b.f = hi;
    return ((a.u + 0x8000u) >> 16) | (((b.u + 0x8000u) >> 16) << 16);
}
// split two floats into packed hi-pair and lo-pair (double-bf16, RNE)
__device__ __forceinline__ void split2(float a, float b, unsigned& hi, unsigned& lo) {
    const unsigned short ah = f2bf(a), bh = f2bf(b);
    const unsigned short al = f2bf(a - bf2f(ah)), bl = f2bf(b - bf2f(bh));
    hi = (unsigned)ah | ((unsigned)bh << 16);
    lo = (unsigned)al | ((unsigned)bl << 16);
}
// relu on 8 packed bf16: zero each half whose sign bit is set
__device__ __forceinline__ bf16x8 relu8(bf16x8 x) {
    union { bf16x8 v; unsigned u[4]; } a; a.v = x;
    #pragma unroll
    for (int i = 0; i < 4; ++i) {
        unsigned s = a.u[i] & 0x80008000u;
        a.u[i] &= ~((s >> 15) * 0xFFFFu);
    }
    return a.v;
}

// ---- kernel 1 (64 blocks): layernorms + hat0 + hi/lo weight prep, spread wide
__global__ __launch_bounds__(256) void prep_kernel(
    const float* __restrict__ emb_column,  // [C,H]
    const float* __restrict__ emb_prompt,  // [P,H]
    const float* __restrict__ lin_w,       // [H,2H]
    const float* __restrict__ lin_b,       // [H]
    const float* __restrict__ ln_col_w, const float* __restrict__ ln_col_b,
    const float* __restrict__ ln_pr_w,  const float* __restrict__ ln_pr_b,
    float* __restrict__ hat0,              // ws: [P,H] = ep@W1^T + lin_b + ep
    unsigned short* __restrict__ ec_hi,    // ws: [C,H]
    unsigned short* __restrict__ ec_lo,    // ws: [C,H]
    unsigned short* __restrict__ w2_hi,    // ws: [H,H], [h][k]=lin_w[h][H+k]
    unsigned short* __restrict__ w2_lo)    // ws: [H,H]
{
    __shared__ __align__(16) float ep_row[H_];
    const int t = threadIdx.x;
    const int blk = blockIdx.x;
    const int lane = t & 63;
    const int w = t >> 6;

    if (blk < 16) {
        // --- ep layernorm for row p=blk (wave 0), then hat0 row p ---
        const int p = blk;
        const float v0 = emb_prompt[p * H_ + lane];
        const float v1 = emb_prompt[p * H_ + lane + 64];
        float s = v0 + v1, s2 = v0 * v0 + v1 * v1;
        #pragma unroll
        for (int m = 1; m < 64; m <<= 1) { s += __shfl_xor(s, m, 64); s2 += __shfl_xor(s2, m, 64); }
        const float mean = s * (1.f / H_);
        const float rs = rsqrtf(s2 * (1.f / H_) - mean * mean + EPS);
        if (w == 0) {
            ep_row[lane]      = (v0 - mean) * rs * ln_pr_w[lane]      + ln_pr_b[lane];
            ep_row[lane + 64] = (v1 - mean) * rs * ln_pr_w[lane + 64] + ln_pr_b[lane + 64];
        }
        __syncthreads();
        // hat0[p][h]: 2 threads per h, each half of K
        const int h = t >> 1;
        const int kh = (t & 1) * 16;  // float4 units
        const float4* w1 = (const float4*)(lin_w + h * (2 * H_)) + kh;
        const float4* e4 = (const float4*)ep_row + kh;
        float acc = 0.f;
        #pragma unroll
        for (int k = 0; k < 16; ++k) {
            const float4 W = w1[k], E = e4[k];
            acc += E.x * W.x + E.y * W.y + E.z * W.z + E.w * W.w;
        }
        acc += __shfl_xor(acc, 1, 64);
        if ((t & 1) == 0) hat0[p * H_ + h] = acc + lin_b[h] + ep_row[h];
    } else if (blk < 32) {
        // --- ec layernorm -> hi/lo: one row per wave ---
        const int r = (blk - 16) * 4 + w;
        const float v0 = emb_column[r * H_ + lane];
        const float v1 = emb_column[r * H_ + lane + 64];
        float s = v0 + v1, s2 = v0 * v0 + v1 * v1;
        #pragma unroll
        for (int m = 1; m < 64; m <<= 1) { s += __shfl_xor(s, m, 64); s2 += __shfl_xor(s2, m, 64); }
        const float mean = s * (1.f / H_);
        const float rs = rsqrtf(s2 * (1.f / H_) - mean * mean + EPS);
        const float a0 = (v0 - mean) * rs * ln_col_w[lane]      + ln_col_b[lane];
        const float a1 = (v1 - mean) * rs * ln_col_w[lane + 64] + ln_col_b[lane + 64];
        const unsigned short h0 = f2bf(a0), h1 = f2bf(a1);
        ec_hi[r * H_ + lane]      = h0;
        ec_hi[r * H_ + lane + 64] = h1;
        ec_lo[r * H_ + lane]      = f2bf(a0 - bf2f(h0));
        ec_lo[r * H_ + lane + 64] = f2bf(a1 - bf2f(h1));
    } else {
        // --- w2 hi/lo split: 512 elements per block, 2 per thread ---
        const int f = (blk - 32) * 512 + t * 2;
        const int h = f >> 7, k = f & 127;
        const float2 q = *(const float2*)(lin_w + h * (2 * H_) + H_ + k);
        unsigned hi, lo;
        split2(q.x, q.y, hi, lo);
        *(unsigned*)(w2_hi + f) = hi;
        *(unsigned*)(w2_lo + f) = lo;
    }
}

// ---------------- kernel 2: one block per batch element, MFMA + hi/lo --------
__global__ __launch_bounds__(256) void main_kernel(
    const float* __restrict__ x,         // [B,C,H]
    const float* __restrict__ x_prompt,  // [B,P,H]
    const float* __restrict__ expand_w,  // [P]
    const float* __restrict__ gn_w, const float* __restrict__ gn_b,  // [P]
    const float* __restrict__ hat0,             // [P,H] fp32
    const unsigned short* __restrict__ ec_hi,   // [C,H]
    const unsigned short* __restrict__ ec_lo,
    const unsigned short* __restrict__ w2_hi,   // [H,H]
    const unsigned short* __restrict__ w2_lo,
    float* __restrict__ out)             // [B,P,H]
{
    __shared__ __align__(16) unsigned short xs_bf[C_ * XS_S];    // 16640 B
    __shared__ __align__(16) unsigned short xp_hi[P_ * HB_S];    // 4352 B
    __shared__ __align__(16) unsigned short xp_lo[P_ * HB_S];    // 4352 B
    __shared__ __align__(16) unsigned short hat_hi[P_ * HB_S];   // 4352 B
    __shared__ __align__(16) unsigned short hat_lo[P_ * HB_S];   // 4352 B
    __shared__ __align__(16) float sm[P_ * C_];                  // 4096 B
    __shared__ __align__(16) unsigned short m_bf[P_ * MB_S];     // 2304 B
    __shared__ float red[16];
    __shared__ float stat[4];   // Xsum, Xsq, R1=sum relu(x), R2=sum relu(x)^2
    __shared__ float s1_s[P_], s2_s[P_];
    __shared__ float cA[P_], cB[P_], cD[P_];

    const int t = threadIdx.x;
    const int b = blockIdx.x;
    const int lane = t & 63;
    const int w = t >> 6;       // wave id 0..3
    const int nl = lane & 15;   // MFMA n/m lane coord
    const int quad = lane >> 4; // MFMA quad

    // prefetch phase-B epilogue operands (latency overlaps phase-A staging)
    float h0r[2][4], xpr[2][4];
    {
        const float* xpg = x_prompt + (size_t)b * (P_ * H_);
        #pragma unroll
        for (int T = 0; T < 2; ++T) {
            const int h = w * 32 + T * 16 + nl;
            #pragma unroll
            for (int r = 0; r < 4; ++r) {
                const int p = quad * 4 + r;
                h0r[T][r] = hat0[p * H_ + h];
                xpr[T][r] = xpg[p * H_ + h];
            }
        }
    }

    // ---- phase A: x[b] -> bf16 LDS + stats; x_prompt[b] -> hi/lo LDS ----
    {
        const float4* x4 = (const float4*)(x + (size_t)b * (C_ * H_));
        float xsum = 0.f, xsq = 0.f, r1 = 0.f, r2 = 0.f;
        #pragma unroll
        for (int i = 0; i < 8; ++i) {
            const int idx = t + 256 * i;
            const float4 v = x4[idx];
            const int c = idx >> 5;
            const int h0 = (idx & 31) * 4;
            unsigned* dst = (unsigned*)(xs_bf + c * XS_S + h0);
            dst[0] = packbf_fast(v.x, v.y);
            dst[1] = packbf_fast(v.z, v.w);
            xsum += (v.x + v.y) + (v.z + v.w);
            xsq  += (v.x * v.x + v.y * v.y) + (v.z * v.z + v.w * v.w);
            const float rx = fmaxf(v.x, 0.f), ry = fmaxf(v.y, 0.f);
            const float rz = fmaxf(v.z, 0.f), rw = fmaxf(v.w, 0.f);
            r1 += (rx + ry) + (rz + rw);
            r2 += (rx * rx + ry * ry) + (rz * rz + rw * rw);
        }
        #pragma unroll
        for (int m = 1; m < 64; m <<= 1) {
            xsum += __shfl_xor(xsum, m, 64);
            xsq  += __shfl_xor(xsq,  m, 64);
            r1   += __shfl_xor(r1,   m, 64);
            r2   += __shfl_xor(r2,   m, 64);
        }
        if (lane == 0) {
            red[w * 4 + 0] = xsum; red[w * 4 + 1] = xsq;
            red[w * 4 + 2] = r1;   red[w * 4 + 3] = r2;
        }
        // xp -> hi/lo LDS: 8 consecutive values per thread
        const float4* xp4 = (const float4*)(x_prompt + (size_t)b * (P_ * H_));
        const float4 a0 = xp4[2 * t], a1 = xp4[2 * t + 1];
        const int p = t >> 4, hh = (t & 15) * 8;
        uint4 ph, pl;
        split2(a0.x, a0.y, ph.x, pl.x);
        split2(a0.z, a0.w, ph.y, pl.y);
        split2(a1.x, a1.y, ph.z, pl.z);
        split2(a1.z, a1.w, ph.w, pl.w);
        *(uint4*)(xp_hi + p * HB_S + hh) = ph;
        *(uint4*)(xp_lo + p * HB_S + hh) = pl;
    }
    __syncthreads();
    if (t < 4) stat[t] = red[t] + red[4 + t] + red[8 + t] + red[12 + t];

    // ---- phase B (MFMA, hi/lo): hat = xp@W2^T + hat0 + xp ; store hi/lo ----
    {
        f32x4 acc[2] = {{0.f,0.f,0.f,0.f},{0.f,0.f,0.f,0.f}};
        #pragma unroll
        for (int kk = 0; kk < 4; ++kk) {
            const bf16x8 a_hi = *(const bf16x8*)(xp_hi + nl * HB_S + kk * 32 + quad * 8);
            const bf16x8 a_lo = *(const bf16x8*)(xp_lo + nl * HB_S + kk * 32 + quad * 8);
            #pragma unroll
            for (int T = 0; T < 2; ++T) {
                const int h = w * 32 + T * 16 + nl;
                const bf16x8 b_hi = *(const bf16x8*)(w2_hi + h * H_ + kk * 32 + quad * 8);
                const bf16x8 b_lo = *(const bf16x8*)(w2_lo + h * H_ + kk * 32 + quad * 8);
                acc[T] = __builtin_amdgcn_mfma_f32_16x16x32_bf16(a_hi, b_hi, acc[T], 0, 0, 0);
                acc[T] = __builtin_amdgcn_mfma_f32_16x16x32_bf16(a_lo, b_hi, acc[T], 0, 0, 0);
                acc[T] = __builtin_amdgcn_mfma_f32_16x16x32_bf16(a_hi, b_lo, acc[T], 0, 0, 0);
            }
        }
        #pragma unroll
        for (int T = 0; T < 2; ++T) {
            const int h = w * 32 + T * 16 + nl;
            #pragma unroll
            for (int r = 0; r < 4; ++r) {
                const int p = quad * 4 + r;
                const float val = acc[T][r] + h0r[T][r] + xpr[T][r];
                const unsigned short hi = f2bf(val);
                hat_hi[p * HB_S + h] = hi;
                hat_lo[p * HB_S + h] = f2bf(val - bf2f(hi));
            }
        }
    }
    __syncthreads();

    // ---- group-norm per-p partial sums (uses stat) ----
    if (t < P_) {
        const float ew = expand_w[t];
        const float Ap = fabsf(ew);
        const float Bp = fminf(ew, 0.f);
        s1_s[t] = Ap * stat[2] + Bp * stat[0];
        s2_s[t] = ew * ew * (ew >= 0.f ? stat[3] : (stat[1] - stat[3]));
    }
    // ---- phase C (MFMA, hi/lo): scores[p][c] = hat @ ec^T ----
    {
        f32x4 acc = {0.f, 0.f, 0.f, 0.f};
        const int c = w * 16 + nl;
        #pragma unroll
        for (int kk = 0; kk < 4; ++kk) {
            const bf16x8 a_hi = *(const bf16x8*)(hat_hi + nl * HB_S + kk * 32 + quad * 8);
            const bf16x8 a_lo = *(const bf16x8*)(hat_lo + nl * HB_S + kk * 32 + quad * 8);
            const bf16x8 b_hi = *(const bf16x8*)(ec_hi + c * H_ + kk * 32 + quad * 8);
            const bf16x8 b_lo = *(const bf16x8*)(ec_lo + c * H_ + kk * 32 + quad * 8);
            acc = __builtin_amdgcn_mfma_f32_16x16x32_bf16(a_hi, b_hi, acc, 0, 0, 0);
            acc = __builtin_amdgcn_mfma_f32_16x16x32_bf16(a_lo, b_hi, acc, 0, 0, 0);
            acc = __builtin_amdgcn_mfma_f32_16x16x32_bf16(a_hi, b_lo, acc, 0, 0, 0);
        }
        #pragma unroll
        for (int r = 0; r < 4; ++r) sm[(quad * 4 + r) * C_ + c] = acc[r];
    }
    __syncthreads();

    // ---- phase D: coeffs + softmax (fp32) -> m_bf ----
    if (t < P_) {
        const int g = t >> 3;
        float S1 = 0.f, S2 = 0.f;
        #pragma unroll
        for (int q = 0; q < 8; ++q) { S1 += s1_s[g * 8 + q]; S2 += s2_s[g * 8 + q]; }
        const float invN = 1.f / (float)((P_ / G_) * C_ * H_);
        const float mu = S1 * invN;
        const float var = S2 * invN - mu * mu;
        const float rs = rsqrtf(var + EPS);
        const float a = rs * gn_w[t];
        const float ew = expand_w[t];
        cA[t] = a * fabsf(ew);             // coeff on TR = sum_c m*relu(x)
        cB[t] = a * fminf(ew, 0.f) + 1.f;  // coeff on U = sum_c m*x (+1 residual)
        cD[t] = gn_b[t] - mu * a;          // constant (sum_c m == 1)
    }
    {
        const int p = t >> 4, j = t & 15;
        float v0 = sm[p * C_ + j],      v1 = sm[p * C_ + j + 16];
        float v2 = sm[p * C_ + j + 32], v3 = sm[p * C_ + j + 48];
        float mx = fmaxf(fmaxf(v0, v1), fmaxf(v2, v3));
        #pragma unroll
        for (int m = 1; m < 16; m <<= 1) mx = fmaxf(mx, __shfl_xor(mx, m, 64));
        const float e0 = __expf(v0 - mx), e1 = __expf(v1 - mx);
        const float e2 = __expf(v2 - mx), e3 = __expf(v3 - mx);
        float ssum = (e0 + e1) + (e2 + e3);
        #pragma unroll
        for (int m = 1; m < 16; m <<= 1) ssum += __shfl_xor(ssum, m, 64);
        const float inv = 1.f / ssum;
        m_bf[p * MB_S + j]      = f2bf(e0 * inv);
        m_bf[p * MB_S + j + 16] = f2bf(e1 * inv);
        m_bf[p * MB_S + j + 32] = f2bf(e2 * inv);
        m_bf[p * MB_S + j + 48] = f2bf(e3 * inv);
    }
    __syncthreads();

    // ---- phase E (MFMA): U = m@x, TR = m@relu(x); out = cA*TR + cB*U + cD ----
    {
        f32x4 aU[2] = {{0.f,0.f,0.f,0.f},{0.f,0.f,0.f,0.f}};
        f32x4 aT[2] = {{0.f,0.f,0.f,0.f},{0.f,0.f,0.f,0.f}};
        #pragma unroll
        for (int kk = 0; kk < 2; ++kk) {
            const bf16x8 af = *(const bf16x8*)(m_bf + nl * MB_S + kk * 32 + quad * 8);
            #pragma unroll
            for (int T = 0; T < 2; ++T) {
                const int h = w * 32 + T * 16 + nl;
                // B-frag: x[c][h] for c = kk*32 + quad*8 + j (column read, 2-way banks)
                union { bf16x8 v; unsigned short s[8]; } bu;
                const int c0 = kk * 32 + quad * 8;
                #pragma unroll
                for (int j = 0; j < 8; ++j) bu.s[j] = xs_bf[(c0 + j) * XS_S + h];
                aU[T] = __builtin_amdgcn_mfma_f32_16x16x32_bf16(af, bu.v, aU[T], 0, 0, 0);
                const bf16x8 br = relu8(bu.v);
                aT[T] = __builtin_amdgcn_mfma_f32_16x16x32_bf16(af, br, aT[T], 0, 0, 0);
            }
        }
        float* ob = out + (size_t)b * (P_ * H_);
        #pragma unroll
        for (int T = 0; T < 2; ++T) {
            const int h = w * 32 + T * 16 + nl;
            #pragma unroll
            for (int r = 0; r < 4; ++r) {
                const int p = quad * 4 + r;
                ob[p * H_ + h] = cA[p] * aT[T][r] + cB[p] * aU[T][r] + cD[p];
            }
        }
    }
}

extern "C" void kernel_launch(void* const* d_in, const int* in_sizes, int n_in,
                              void* d_out, int out_size, void* d_ws, size_t ws_size,
                              hipStream_t stream) {
    const float* x          = (const float*)d_in[0];
    const float* x_prompt   = (const float*)d_in[1];
    const float* emb_column = (const float*)d_in[2];
    const float* emb_prompt = (const float*)d_in[3];
    const float* lin_w      = (const float*)d_in[4];
    const float* lin_b      = (const float*)d_in[5];
    const float* ln_col_w   = (const float*)d_in[6];
    const float* ln_col_b   = (const float*)d_in[7];
    const float* ln_pr_w    = (const float*)d_in[8];
    const float* ln_pr_b    = (const float*)d_in[9];
    const float* expand_w   = (const float*)d_in[10];
    const float* gn_w       = (const float*)d_in[11];
    const float* gn_b       = (const float*)d_in[12];
    float* out = (float*)d_out;

    float* hat0 = (float*)d_ws;                                 // [P,H] fp32
    unsigned short* ec_hi = (unsigned short*)(hat0 + P_ * H_);  // [C,H]
    unsigned short* ec_lo = ec_hi + C_ * H_;                    // [C,H]
    unsigned short* w2_hi = ec_lo + C_ * H_;                    // [H,H]
    unsigned short* w2_lo = w2_hi + H_ * H_;                    // [H,H]

    prep_kernel<<<64, 256, 0, stream>>>(emb_column, emb_prompt, lin_w, lin_b,
                                        ln_col_w, ln_col_b, ln_pr_w, ln_pr_b,
                                        hat0, ec_hi, ec_lo, w2_hi, w2_lo);
    main_kernel<<<B_, 256, 0, stream>>>(x, x_prompt, expand_w, gn_w, gn_b,
                                        hat0, ec_hi, ec_lo, w2_hi, w2_lo, out);
}